// Round 4
// baseline (132.062 us; speedup 1.0000x reference)
//
#include <hip/hip_runtime.h>

typedef float f32x4 __attribute__((ext_vector_type(4)));
typedef short s16x8 __attribute__((ext_vector_type(8)));

#define MFMA16(a, b, c) __builtin_amdgcn_mfma_f32_16x16x32_bf16((a), (b), (c), 0, 0, 0)

#define B_ 16
#define M_ 6209
#define F_ 256
#define H_ 64
#define J_ 256

static __device__ __forceinline__ unsigned short f2bf(float x) {
    unsigned u = __builtin_bit_cast(unsigned, x);
    unsigned r = u + 0x7fffu + ((u >> 16) & 1u);
    return (unsigned short)(r >> 16);
}
static __device__ __forceinline__ float bf2f(unsigned short h) {
    unsigned u = ((unsigned)h) << 16;
    return __builtin_bit_cast(float, u);
}
static __device__ __forceinline__ void split_bf(float x, unsigned short& hi, unsigned short& lo) {
    hi = f2bf(x);
    lo = f2bf(x - bf2f(hi));
}
static __device__ __forceinline__ unsigned cvtpk_bf16(float a, float b) {
    unsigned r;
    asm("v_cvt_pk_bf16_f32 %0, %1, %2" : "=v"(r) : "v"(a), "v"(b));
    return r;   // lo16 = bf(a), hi16 = bf(b)
}

// ---------------- S1: mapped_b = input_b @ Wb + bb  (exact fp32) ----------------
__global__ void k_mapped_b(const float* __restrict__ inB, const float* __restrict__ Wb,
                           const float* __restrict__ bb, float* __restrict__ mb) {
    int bj = blockIdx.x;            // 0 .. 16*256-1
    int b = bj >> 8, j = bj & 255;
    __shared__ float row[256];
    int t = threadIdx.x;            // 64 threads, t = h
    const float* src = inB + ((size_t)(b * 256 + j)) * 256;
    for (int i = t; i < 256; i += 64) row[i] = src[i];
    __syncthreads();
    float s = bb[t];
    #pragma unroll 8
    for (int f = 0; f < 256; ++f) s = fmaf(row[f], Wb[f * 64 + t], s);
    mb[(size_t)(b * 256 + j) * 64 + t] = s;
}

// ---------------- S2: pack fragment-ordered operand buffers (unchanged) ----------------
__global__ void k_pack(const float* __restrict__ mb, const float* __restrict__ Wa,
                       const float* __restrict__ Wc,
                       unsigned short* __restrict__ waf_hi, unsigned short* __restrict__ waf_lo,
                       unsigned short* __restrict__ wcf,
                       unsigned short* __restrict__ mbb_hi, unsigned short* __restrict__ mbb_lo,
                       unsigned short* __restrict__ mbp) {
    int idx = blockIdx.x * 256 + threadIdx.x;
    if (idx < 16384) {                      // WaF: K=256(f), N=64(h), split
        int i = idx;
        int jj = i & 7, lane = (i >> 3) & 63, nf = (i >> 9) & 3, ks = i >> 11;
        int g = lane >> 4, c = lane & 15;
        int f = ks * 32 + g * 8 + jj, h = nf * 16 + c;
        unsigned short hi, lo; split_bf(Wa[f * 64 + h], hi, lo);
        waf_hi[i] = hi; waf_lo[i] = lo;
    } else if (idx < 32768) {               // WcF: K=64(h), N=256(f), single
        int i = idx - 16384;
        int jj = i & 7, lane = (i >> 3) & 63, nf = (i >> 9) & 15, ks = i >> 13;
        int g = lane >> 4, c = lane & 15;
        int h = ks * 32 + g * 8 + jj, f = nf * 16 + c;
        wcf[i] = f2bf(Wc[h * 256 + f]);
    } else if (idx < 32768 + 262144) {      // mbb: mb[j=nf*16+c][h=ks*32+g*8+jj] split
        int i = idx - 32768;
        int jj = i & 7, lane = (i >> 3) & 63, nf = (i >> 9) & 15, ks = (i >> 13) & 1, b = i >> 14;
        int g = lane >> 4, c = lane & 15;
        int h = ks * 32 + g * 8 + jj, j = nf * 16 + c;
        unsigned short hi, lo; split_bf(mb[((size_t)(b * 256 + j)) * 64 + h], hi, lo);
        mbb_hi[i] = hi; mbb_lo[i] = lo;
    } else {                                 // mbp: mb[j=ks*32+g*8+jj][h=nf*16+c] single
        int i = idx - (32768 + 262144);
        int jj = i & 7, lane = (i >> 3) & 63, nf = (i >> 9) & 3, ks = (i >> 11) & 7, b = i >> 14;
        int g = lane >> 4, c = lane & 15;
        int j = ks * 32 + g * 8 + jj, h = nf * 16 + c;
        mbp[i] = f2bf(mb[((size_t)(b * 256 + j)) * 64 + h]);
    }
}

// ---------------- Main fused kernel: 1 wave = 16 q-rows, end-to-end ----------------
// Swapped-operand scheme: S^T = mfma(A=mb_jtile, B=ma^T) puts all 256 logits of
// q = lane&15 into 64 regs of 4 lanes (g=0..3) -> softmax = in-reg tree + 2 shfl.
// All transposes via per-wave swizzled LDS; no barriers (single-wave block).
__global__ __launch_bounds__(64, 4) void k_main(
    const float* __restrict__ A, const float* __restrict__ ba, const float* __restrict__ bc,
    const unsigned short* __restrict__ waf_hi, const unsigned short* __restrict__ waf_lo,
    const unsigned short* __restrict__ wcf,
    const unsigned short* __restrict__ mbb_hi, const unsigned short* __restrict__ mbb_lo,
    const unsigned short* __restrict__ mbp,
    float* __restrict__ out) {
    __shared__ __align__(16) unsigned short maH[16 * 64];   // ma hi  (2 KB)
    __shared__ __align__(16) unsigned short maL[16 * 64];   // ma lo  (2 KB)
    __shared__ __align__(16) unsigned short pSh[16 * 256];  // P^T bf16, [q][j] (8 KB)
    __shared__ __align__(16) unsigned short o1S[16 * 64];   // out1 bf16, [q][h] (2 KB)

    const int tile = blockIdx.x, b = blockIdx.y;
    const int lane = threadIdx.x & 63;
    const int g = lane >> 4, c = lane & 15;
    const int q0 = tile * 16;
    const float SC = 11.541560327f;   // 8 * log2(e)

    // swizzled u16 index: XOR key (row&7)<<3 spreads banks, preserves 8-u16 chunks
    #define SW64(row, k)  ((row) * 64 + ((k) ^ (((row) & 7) << 3)))
    #define SW256(row, k) ((row) * 256 + ((k) ^ (((row) & 7) << 3)))

    // ---- P1: ma[16 q][64 h] = A_tile @ Wa + ba (split-bf16, 3 products) ----
    f32x4 accA[4];
    #pragma unroll
    for (int nf = 0; nf < 4; ++nf) { float v = ba[nf * 16 + c]; accA[nf] = (f32x4){v, v, v, v}; }
    int arow = q0 + c; if (arow > M_ - 1) arow = M_ - 1;   // clamp tail (stores masked)
    const float* abase = A + ((size_t)b * M_ + arow) * F_;
    #pragma unroll
    for (int ks = 0; ks < 8; ++ks) {
        const f32x4 a0 = *(const f32x4*)(abase + ks * 32 + g * 8);
        const f32x4 a1 = *(const f32x4*)(abase + ks * 32 + g * 8 + 4);
        s16x8 ah, al;
        #pragma unroll
        for (int j = 0; j < 4; ++j) {
            unsigned short hi, lo;
            split_bf(a0[j], hi, lo); ah[j] = (short)hi; al[j] = (short)lo;
            split_bf(a1[j], hi, lo); ah[4 + j] = (short)hi; al[4 + j] = (short)lo;
        }
        #pragma unroll
        for (int nf = 0; nf < 4; ++nf) {
            const int off = ((ks * 4 + nf) * 64 + lane) << 3;
            const s16x8 bh = *(const s16x8*)(waf_hi + off);
            const s16x8 bl = *(const s16x8*)(waf_lo + off);
            accA[nf] = MFMA16(ah, bh, accA[nf]);
            accA[nf] = MFMA16(ah, bl, accA[nf]);
            accA[nf] = MFMA16(al, bh, accA[nf]);
        }
    }
    // stash split ma to LDS: D layout row(q-local)=g*4+r, col(h)=nf*16+c
    #pragma unroll
    for (int nf = 0; nf < 4; ++nf) {
        #pragma unroll
        for (int r = 0; r < 4; ++r) {
            unsigned short hi, lo; split_bf(accA[nf][r], hi, lo);
            const int idx = SW64(g * 4 + r, nf * 16 + c);
            maH[idx] = hi; maL[idx] = lo;
        }
    }
    __syncthreads();   // single-wave: compiles to waitcnt only

    // ---- P2: S^T[j=256][q=16]: A = mb tiles (mbb), B = ma^T from LDS ----
    s16x8 bh[2], bl[2];
    #pragma unroll
    for (int ks = 0; ks < 2; ++ks) {
        const int idx = SW64(c, ks * 32 + g * 8);
        bh[ks] = *(const s16x8*)&maH[idx];
        bl[ks] = *(const s16x8*)&maL[idx];
    }
    f32x4 accST[16];   // lane holds S[j = jt*16 + g*4 + r][q = q0 + c]
    #pragma unroll
    for (int jt = 0; jt < 16; ++jt) accST[jt] = (f32x4){0.f, 0.f, 0.f, 0.f};
    #pragma unroll
    for (int jt = 0; jt < 16; ++jt) {
        const size_t off0 = ((((size_t)b * 2 + 0) * 16 + jt) * 64 + lane) << 3;
        const size_t off1 = ((((size_t)b * 2 + 1) * 16 + jt) * 64 + lane) << 3;
        const s16x8 ah0 = *(const s16x8*)(mbb_hi + off0);
        const s16x8 al0 = *(const s16x8*)(mbb_lo + off0);
        const s16x8 ah1 = *(const s16x8*)(mbb_hi + off1);
        const s16x8 al1 = *(const s16x8*)(mbb_lo + off1);
        f32x4 acc = accST[jt];
        acc = MFMA16(ah0, bh[0], acc);
        acc = MFMA16(ah1, bh[1], acc);
        acc = MFMA16(ah0, bl[0], acc);
        acc = MFMA16(ah1, bl[1], acc);
        acc = MFMA16(al0, bh[0], acc);
        acc = MFMA16(al1, bh[1], acc);
        accST[jt] = acc;
    }

    // ---- P3: softmax over j for q=c (64 regs in-lane + lanes c,c+16,c+32,c+48) ----
    f32x4 vm = accST[0];
    #pragma unroll
    for (int jt = 1; jt < 16; ++jt) {
        vm[0] = fmaxf(vm[0], accST[jt][0]); vm[1] = fmaxf(vm[1], accST[jt][1]);
        vm[2] = fmaxf(vm[2], accST[jt][2]); vm[3] = fmaxf(vm[3], accST[jt][3]);
    }
    float m = fmaxf(fmaxf(vm[0], vm[1]), fmaxf(vm[2], vm[3]));
    m = fmaxf(m, __shfl_xor(m, 16));
    m = fmaxf(m, __shfl_xor(m, 32));
    float s = 0.f;
    #pragma unroll
    for (int jt = 0; jt < 16; ++jt) {
        #pragma unroll
        for (int r = 0; r < 4; ++r) {
            const float pv = __builtin_amdgcn_exp2f((accST[jt][r] - m) * SC);
            accST[jt][r] = pv;
            s += pv;
        }
    }
    s += __shfl_xor(s, 16);
    s += __shfl_xor(s, 32);
    const float rinv = 1.f / s;
    // P^T -> LDS [q][j] bf16 (unnormalized; 1/s folded into out1)
    #pragma unroll
    for (int jt = 0; jt < 16; ++jt) {
        const unsigned w0 = cvtpk_bf16(accST[jt][0], accST[jt][1]);
        const unsigned w1 = cvtpk_bf16(accST[jt][2], accST[jt][3]);
        const unsigned long long wv = (unsigned long long)w0 | ((unsigned long long)w1 << 32);
        *(unsigned long long*)&pSh[SW256(c, jt * 16 + g * 4)] = wv;
    }
    __syncthreads();

    // ---- P4: out1^T[h][q] = mfma(A=mb^T (mbp), B=P^T from LDS), K=256 ----
    s16x8 pf[8];
    #pragma unroll
    for (int ks = 0; ks < 8; ++ks)
        pf[ks] = *(const s16x8*)&pSh[SW256(c, ks * 32 + g * 8)];
    f32x4 acc1[4];
    #pragma unroll
    for (int ht = 0; ht < 4; ++ht) acc1[ht] = (f32x4){0.f, 0.f, 0.f, 0.f};
    #pragma unroll
    for (int ht = 0; ht < 4; ++ht) {
        #pragma unroll
        for (int ks = 0; ks < 8; ++ks) {
            const size_t off = ((((size_t)b * 8 + ks) * 4 + ht) * 64 + lane) << 3;
            const s16x8 av = *(const s16x8*)(mbp + off);
            acc1[ht] = MFMA16(av, pf[ks], acc1[ht]);
        }
    }
    // out1 (normalized) -> LDS [q][h] bf16;  D: row(h)=ht*16+g*4+r, col(q)=c
    #pragma unroll
    for (int ht = 0; ht < 4; ++ht) {
        const unsigned w0 = cvtpk_bf16(acc1[ht][0] * rinv, acc1[ht][1] * rinv);
        const unsigned w1 = cvtpk_bf16(acc1[ht][2] * rinv, acc1[ht][3] * rinv);
        const unsigned long long wv = (unsigned long long)w0 | ((unsigned long long)w1 << 32);
        *(unsigned long long*)&o1S[SW64(c, ht * 16 + g * 4)] = wv;
    }
    __syncthreads();

    // ---- P5: out = out1 @ Wc + bc;  A = out1 (rows q), B = wcf ----
    s16x8 af[2];
    #pragma unroll
    for (int ks = 0; ks < 2; ++ks)
        af[ks] = *(const s16x8*)&o1S[SW64(c, ks * 32 + g * 8)];
    #pragma unroll
    for (int ft = 0; ft < 16; ++ft) {
        const float bv = bc[ft * 16 + c];
        f32x4 acc = (f32x4){bv, bv, bv, bv};
        const s16x8 wb0 = *(const s16x8*)(wcf + (((0 * 16 + ft) * 64 + lane) << 3));
        const s16x8 wb1 = *(const s16x8*)(wcf + (((1 * 16 + ft) * 64 + lane) << 3));
        acc = MFMA16(af[0], wb0, acc);
        acc = MFMA16(af[1], wb1, acc);
        #pragma unroll
        for (int r = 0; r < 4; ++r) {
            const int q = q0 + g * 4 + r;
            if (q < M_) out[((size_t)b * M_ + q) * F_ + ft * 16 + c] = acc[r];
        }
    }
    #undef SW64
    #undef SW256
}

extern "C" void kernel_launch(void* const* d_in, const int* in_sizes, int n_in,
                              void* d_out, int out_size, void* d_ws, size_t ws_size,
                              hipStream_t stream) {
    (void)in_sizes; (void)n_in; (void)out_size; (void)ws_size;
    const float* inA = (const float*)d_in[0];
    const float* inB = (const float*)d_in[1];
    const float* Wa  = (const float*)d_in[2];
    const float* ba  = (const float*)d_in[3];
    const float* Wb  = (const float*)d_in[4];
    const float* bb  = (const float*)d_in[5];
    const float* Wc  = (const float*)d_in[6];
    const float* bc  = (const float*)d_in[7];
    float* out = (float*)d_out;

    char* ws = (char*)d_ws;
    float* mb              = (float*)ws;                          // 1,048,576 B
    unsigned short* waf_hi = (unsigned short*)(ws + 1048576);     //    32,768 B
    unsigned short* waf_lo = (unsigned short*)(ws + 1081344);     //    32,768 B
    unsigned short* wcf    = (unsigned short*)(ws + 1114112);     //    32,768 B
    unsigned short* mbb_hi = (unsigned short*)(ws + 1146880);     //   524,288 B
    unsigned short* mbb_lo = (unsigned short*)(ws + 1671168);     //   524,288 B
    unsigned short* mbp    = (unsigned short*)(ws + 2195456);     //   524,288 B  (end ~2.72 MB)

    hipLaunchKernelGGL(k_mapped_b, dim3(B_ * J_), dim3(64), 0, stream, inB, Wb, bb, mb);
    hipLaunchKernelGGL(k_pack, dim3((557056 + 255) / 256), dim3(256), 0, stream,
                       mb, Wa, Wc, waf_hi, waf_lo, wcf, mbb_hi, mbb_lo, mbp);
    hipLaunchKernelGGL(k_main, dim3((M_ + 15) / 16, B_), dim3(64), 0, stream,
                       inA, ba, bc, waf_hi, waf_lo, wcf, mbb_hi, mbb_lo, mbp, out);
}

// Round 5
// 92.533 us; speedup vs baseline: 1.4272x; 1.4272x over previous
//
#include <hip/hip_runtime.h>

typedef float f32x4 __attribute__((ext_vector_type(4)));
typedef short s16x8 __attribute__((ext_vector_type(8)));

#define MFMA16(a, b, c) __builtin_amdgcn_mfma_f32_16x16x32_bf16((a), (b), (c), 0, 0, 0)

#define B_ 16
#define M_ 6209
#define F_ 256
#define NTR_ 389   // real 16-row tiles (389*16 = 6224 >= 6209)
#define NT_ 392    // padded tile count (k_ma grid 98*4)

static __device__ __forceinline__ unsigned short f2bf(float x) {
    unsigned u = __builtin_bit_cast(unsigned, x);
    unsigned r = u + 0x7fffu + ((u >> 16) & 1u);
    return (unsigned short)(r >> 16);
}
static __device__ __forceinline__ float bf2f(unsigned short h) {
    unsigned u = ((unsigned)h) << 16;
    return __builtin_bit_cast(float, u);
}
static __device__ __forceinline__ void split_bf(float x, unsigned short& hi, unsigned short& lo) {
    hi = f2bf(x);
    lo = f2bf(x - bf2f(hi));
}
static __device__ __forceinline__ unsigned cvtpk_bf16(float a, float b) {
    unsigned r;
    asm("v_cvt_pk_bf16_f32 %0, %1, %2" : "=v"(r) : "v"(a), "v"(b));
    return r;   // lo16 = bf(a), hi16 = bf(b)
}

// swizzled u16 index: XOR key (row&7)<<3 spreads banks, preserves 8-u16 chunks
#define SW64(row, k)  ((row) * 64 + ((k) ^ (((row) & 7) << 3)))
#define SW256(row, k) ((row) * 256 + ((k) ^ (((row) & 7) << 3)))

// ---------------- S1: mapped_b = input_b @ Wb + bb  (exact fp32) ----------------
__global__ void k_mapped_b(const float* __restrict__ inB, const float* __restrict__ Wb,
                           const float* __restrict__ bb, float* __restrict__ mb) {
    int bj = blockIdx.x;            // 0 .. 16*256-1
    int b = bj >> 8, j = bj & 255;
    __shared__ float row[256];
    int t = threadIdx.x;            // 64 threads, t = h
    const float* src = inB + ((size_t)(b * 256 + j)) * 256;
    for (int i = t; i < 256; i += 64) row[i] = src[i];
    __syncthreads();
    float s = bb[t];
    #pragma unroll 8
    for (int f = 0; f < 256; ++f) s = fmaf(row[f], Wb[f * 64 + t], s);
    mb[(size_t)(b * 256 + j) * 64 + t] = s;
}

// ---------------- S2: pack fragment-ordered operand buffers ----------------
__global__ void k_pack(const float* __restrict__ mb, const float* __restrict__ Wa,
                       const float* __restrict__ Wc,
                       unsigned short* __restrict__ waf_hi, unsigned short* __restrict__ waf_lo,
                       unsigned short* __restrict__ wcf,
                       unsigned short* __restrict__ mbb_hi, unsigned short* __restrict__ mbb_lo,
                       unsigned short* __restrict__ mbp) {
    int idx = blockIdx.x * 256 + threadIdx.x;
    if (idx < 16384) {                      // WaF: K=256(f), N=64(h), split
        int i = idx;
        int jj = i & 7, lane = (i >> 3) & 63, nf = (i >> 9) & 3, ks = i >> 11;
        int g = lane >> 4, c = lane & 15;
        int f = ks * 32 + g * 8 + jj, h = nf * 16 + c;
        unsigned short hi, lo; split_bf(Wa[f * 64 + h], hi, lo);
        waf_hi[i] = hi; waf_lo[i] = lo;
    } else if (idx < 32768) {               // WcF: K=64(h), N=256(f), single
        int i = idx - 16384;
        int jj = i & 7, lane = (i >> 3) & 63, nf = (i >> 9) & 15, ks = i >> 13;
        int g = lane >> 4, c = lane & 15;
        int h = ks * 32 + g * 8 + jj, f = nf * 16 + c;
        wcf[i] = f2bf(Wc[h * 256 + f]);
    } else if (idx < 32768 + 262144) {      // mbb: mb[j=nf*16+c][h=ks*32+g*8+jj] split
        int i = idx - 32768;
        int jj = i & 7, lane = (i >> 3) & 63, nf = (i >> 9) & 15, ks = (i >> 13) & 1, b = i >> 14;
        int g = lane >> 4, c = lane & 15;
        int h = ks * 32 + g * 8 + jj, j = nf * 16 + c;
        unsigned short hi, lo; split_bf(mb[((size_t)(b * 256 + j)) * 64 + h], hi, lo);
        mbb_hi[i] = hi; mbb_lo[i] = lo;
    } else {                                 // mbp: mb[j=ks*32+g*8+jj][h=nf*16+c] single
        int i = idx - (32768 + 262144);
        int jj = i & 7, lane = (i >> 3) & 63, nf = (i >> 9) & 3, ks = (i >> 11) & 7, b = i >> 14;
        int g = lane >> 4, c = lane & 15;
        int j = ks * 32 + g * 8 + jj, h = nf * 16 + c;
        mbp[i] = f2bf(mb[((size_t)(b * 256 + j)) * 64 + h]);
    }
}

// ---------------- K1: ma = A @ Wa + ba, output pre-packed as split B-fragments ----
// 4 independent waves per block, wave = one 16-row tile. Writes mafh/mafl so k_attn
// loads its QK^T B-operand fragments directly (4 x 16B loads per tile).
__global__ __launch_bounds__(256) void k_ma(
    const float* __restrict__ A, const float* __restrict__ ba,
    const unsigned short* __restrict__ waf_hi, const unsigned short* __restrict__ waf_lo,
    unsigned short* __restrict__ mafh, unsigned short* __restrict__ mafl) {
    __shared__ __align__(16) unsigned short maH[4][1024];
    __shared__ __align__(16) unsigned short maL[4][1024];
    const int w = threadIdx.x >> 6, lane = threadIdx.x & 63;
    const int g = lane >> 4, c = lane & 15;
    const int t = blockIdx.x * 4 + w, b = blockIdx.y;

    f32x4 accA[4];
    #pragma unroll
    for (int nf = 0; nf < 4; ++nf) { float v = ba[nf * 16 + c]; accA[nf] = (f32x4){v, v, v, v}; }
    int arow = t * 16 + c; if (arow > M_ - 1) arow = M_ - 1;   // clamp tail rows
    const float* abase = A + ((size_t)b * M_ + arow) * F_;
    #pragma unroll
    for (int ks = 0; ks < 8; ++ks) {
        const f32x4 a0 = *(const f32x4*)(abase + ks * 32 + g * 8);
        const f32x4 a1 = *(const f32x4*)(abase + ks * 32 + g * 8 + 4);
        s16x8 ah, al;
        #pragma unroll
        for (int j = 0; j < 4; ++j) {
            unsigned short hi, lo;
            split_bf(a0[j], hi, lo); ah[j] = (short)hi; al[j] = (short)lo;
            split_bf(a1[j], hi, lo); ah[4 + j] = (short)hi; al[4 + j] = (short)lo;
        }
        #pragma unroll
        for (int nf = 0; nf < 4; ++nf) {
            const int off = ((ks * 4 + nf) * 64 + lane) << 3;
            const s16x8 bh = *(const s16x8*)(waf_hi + off);
            const s16x8 bl = *(const s16x8*)(waf_lo + off);
            accA[nf] = MFMA16(ah, bh, accA[nf]);
            accA[nf] = MFMA16(ah, bl, accA[nf]);
            accA[nf] = MFMA16(al, bh, accA[nf]);
        }
    }
    // split result to per-wave LDS: D layout row(q-local)=g*4+r, col(h)=nf*16+c
    #pragma unroll
    for (int nf = 0; nf < 4; ++nf) {
        #pragma unroll
        for (int r = 0; r < 4; ++r) {
            unsigned short hi, lo; split_bf(accA[nf][r], hi, lo);
            const int idx = SW64(g * 4 + r, nf * 16 + c);
            maH[w][idx] = hi; maL[w][idx] = lo;
        }
    }
    __syncthreads();
    // read B-fragments (B[k=h][n=q]: n=c, k=ks*32+g*8+jj) and store packed
    #pragma unroll
    for (int ks = 0; ks < 2; ++ks) {
        const s16x8 fh = *(const s16x8*)&maH[w][SW64(c, ks * 32 + g * 8)];
        const s16x8 fl = *(const s16x8*)&maL[w][SW64(c, ks * 32 + g * 8)];
        const size_t off = (((size_t)(b * NT_ + t) * 2 + ks) * 64 + lane) << 3;
        *(s16x8*)(mafh + off) = fh;
        *(s16x8*)(mafl + off) = fl;
    }
}

// ---------------- K2: fused attention + projection ----------------
// grid (389, 16), block 256 = 4 waves sharing one 16-q tile:
// wave w: j-quarter (QK^T swapped + partial softmax), h-chunk w (PV), f-quarter w (proj)
__global__ __launch_bounds__(256) void k_attn(
    const unsigned short* __restrict__ mafh, const unsigned short* __restrict__ mafl,
    const unsigned short* __restrict__ mbb_hi, const unsigned short* __restrict__ mbb_lo,
    const unsigned short* __restrict__ mbp, const unsigned short* __restrict__ wcf,
    const float* __restrict__ bc, float* __restrict__ out) {
    __shared__ __align__(16) unsigned short pSh[16 * 256];   // P^T bf16 [q][j] (8 KB)
    __shared__ __align__(16) unsigned short o1S[16 * 64];    // out1 bf16 [q][h] (2 KB)
    __shared__ float pmaxS[4][16];
    __shared__ float psumS[4][16];

    const int t = blockIdx.x, b = blockIdx.y;
    const int w = threadIdx.x >> 6, lane = threadIdx.x & 63;
    const int g = lane >> 4, c = lane & 15;
    const int q0 = t * 16;
    const float SC = 11.541560327f;   // 8 * log2(e)

    // ma fragments for this tile (pre-packed by k_ma)
    s16x8 bh[2], bl[2];
    #pragma unroll
    for (int ks = 0; ks < 2; ++ks) {
        const size_t off = (((size_t)(b * NT_ + t) * 2 + ks) * 64 + lane) << 3;
        bh[ks] = *(const s16x8*)(mafh + off);
        bl[ks] = *(const s16x8*)(mafl + off);
    }

    // ---- QK^T (swapped): S^T[j = (w*4+jtl)*16 + g*4 + r][q = c], j-quarter w ----
    f32x4 accST[4];
    #pragma unroll
    for (int jtl = 0; jtl < 4; ++jtl) accST[jtl] = (f32x4){0.f, 0.f, 0.f, 0.f};
    #pragma unroll
    for (int jtl = 0; jtl < 4; ++jtl) {
        const int jt = w * 4 + jtl;
        const size_t off0 = ((((size_t)b * 2 + 0) * 16 + jt) * 64 + lane) << 3;
        const size_t off1 = ((((size_t)b * 2 + 1) * 16 + jt) * 64 + lane) << 3;
        const s16x8 ah0 = *(const s16x8*)(mbb_hi + off0);
        const s16x8 al0 = *(const s16x8*)(mbb_lo + off0);
        const s16x8 ah1 = *(const s16x8*)(mbb_hi + off1);
        const s16x8 al1 = *(const s16x8*)(mbb_lo + off1);
        f32x4 acc = accST[jtl];
        acc = MFMA16(ah0, bh[0], acc);
        acc = MFMA16(ah1, bh[1], acc);
        acc = MFMA16(ah0, bl[0], acc);
        acc = MFMA16(ah1, bl[1], acc);
        acc = MFMA16(al0, bh[0], acc);
        acc = MFMA16(al1, bh[1], acc);
        accST[jtl] = acc;
    }

    // ---- partial softmax: wave-local max over 64 j for q=c ----
    float m = accST[0][0];
    #pragma unroll
    for (int jtl = 0; jtl < 4; ++jtl) {
        m = fmaxf(m, accST[jtl][0]); m = fmaxf(m, accST[jtl][1]);
        m = fmaxf(m, accST[jtl][2]); m = fmaxf(m, accST[jtl][3]);
    }
    m = fmaxf(m, __shfl_xor(m, 16));
    m = fmaxf(m, __shfl_xor(m, 32));
    if (lane < 16) pmaxS[w][lane] = m;
    __syncthreads();   // B1: pmaxS ready

    const float mg = fmaxf(fmaxf(pmaxS[0][c], pmaxS[1][c]),
                           fmaxf(pmaxS[2][c], pmaxS[3][c]));
    float s = 0.f;
    #pragma unroll
    for (int jtl = 0; jtl < 4; ++jtl) {
        f32x4 p;
        #pragma unroll
        for (int r = 0; r < 4; ++r) {
            p[r] = __builtin_amdgcn_exp2f((accST[jtl][r] - mg) * SC);
            s += p[r];
        }
        const unsigned w0 = cvtpk_bf16(p[0], p[1]);
        const unsigned w1 = cvtpk_bf16(p[2], p[3]);
        const unsigned long long wv = (unsigned long long)w0 | ((unsigned long long)w1 << 32);
        *(unsigned long long*)&pSh[SW256(c, (w * 4 + jtl) * 16 + g * 4)] = wv;
    }
    s += __shfl_xor(s, 16);
    s += __shfl_xor(s, 32);
    if (lane < 16) psumS[w][lane] = s;
    __syncthreads();   // B2: pSh + psumS ready

    // ---- PV: out1^T[h = w*16+g*4+r][q = c], K=256 over all j from LDS P ----
    f32x4 acc1 = (f32x4){0.f, 0.f, 0.f, 0.f};
    #pragma unroll
    for (int ks = 0; ks < 8; ++ks) {
        const s16x8 pf = *(const s16x8*)&pSh[SW256(c, ks * 32 + g * 8)];
        const size_t off = ((((size_t)b * 8 + ks) * 4 + w) * 64 + lane) << 3;
        const s16x8 av = *(const s16x8*)(mbp + off);
        acc1 = MFMA16(av, pf, acc1);
    }
    const float rinv = 1.f / (psumS[0][c] + psumS[1][c] + psumS[2][c] + psumS[3][c]);
    {
        const unsigned w0 = cvtpk_bf16(acc1[0] * rinv, acc1[1] * rinv);
        const unsigned w1 = cvtpk_bf16(acc1[2] * rinv, acc1[3] * rinv);
        const unsigned long long wv = (unsigned long long)w0 | ((unsigned long long)w1 << 32);
        *(unsigned long long*)&o1S[SW64(c, w * 16 + g * 4)] = wv;
    }
    __syncthreads();   // B3: o1S ready

    // ---- projection f-quarter w: out = out1 @ Wc + bc ----
    s16x8 af[2];
    #pragma unroll
    for (int ks = 0; ks < 2; ++ks)
        af[ks] = *(const s16x8*)&o1S[SW64(c, ks * 32 + g * 8)];
    #pragma unroll
    for (int ftl = 0; ftl < 4; ++ftl) {
        const int ft = w * 4 + ftl;
        const float bv = bc[ft * 16 + c];
        f32x4 acc = (f32x4){bv, bv, bv, bv};
        const s16x8 wb0 = *(const s16x8*)(wcf + (((0 * 16 + ft) * 64 + lane) << 3));
        const s16x8 wb1 = *(const s16x8*)(wcf + (((1 * 16 + ft) * 64 + lane) << 3));
        acc = MFMA16(af[0], wb0, acc);
        acc = MFMA16(af[1], wb1, acc);
        #pragma unroll
        for (int r = 0; r < 4; ++r) {
            const int q = q0 + g * 4 + r;
            if (q < M_) out[((size_t)b * M_ + q) * F_ + ft * 16 + c] = acc[r];
        }
    }
}

extern "C" void kernel_launch(void* const* d_in, const int* in_sizes, int n_in,
                              void* d_out, int out_size, void* d_ws, size_t ws_size,
                              hipStream_t stream) {
    (void)in_sizes; (void)n_in; (void)out_size; (void)ws_size;
    const float* inA = (const float*)d_in[0];
    const float* inB = (const float*)d_in[1];
    const float* Wa  = (const float*)d_in[2];
    const float* ba  = (const float*)d_in[3];
    const float* Wb  = (const float*)d_in[4];
    const float* bb  = (const float*)d_in[5];
    const float* Wc  = (const float*)d_in[6];
    const float* bc  = (const float*)d_in[7];
    float* out = (float*)d_out;

    char* ws = (char*)d_ws;
    float* mb              = (float*)ws;                          // @0        1,048,576 B
    unsigned short* waf_hi = (unsigned short*)(ws + 1048576);     //    32,768 B
    unsigned short* waf_lo = (unsigned short*)(ws + 1081344);     //    32,768 B
    unsigned short* wcf    = (unsigned short*)(ws + 1114112);     //    32,768 B
    unsigned short* mbb_hi = (unsigned short*)(ws + 1146880);     //   524,288 B
    unsigned short* mbb_lo = (unsigned short*)(ws + 1671168);     //   524,288 B
    unsigned short* mbp    = (unsigned short*)(ws + 2195456);     //   524,288 B (ends 2,719,744)
    unsigned short* mafh   = (unsigned short*)(ws + 2719744);     // 12,845,056 B (16*392*2*64*8 u16)
    unsigned short* mafl   = (unsigned short*)(ws + 15564800);    // 12,845,056 B (ends 28,409,856)

    hipLaunchKernelGGL(k_mapped_b, dim3(B_ * 256), dim3(64), 0, stream, inB, Wb, bb, mb);
    hipLaunchKernelGGL(k_pack, dim3((557056 + 255) / 256), dim3(256), 0, stream,
                       mb, Wa, Wc, waf_hi, waf_lo, wcf, mbb_hi, mbb_lo, mbp);
    hipLaunchKernelGGL(k_ma, dim3(98, B_), dim3(256), 0, stream,
                       inA, ba, waf_hi, waf_lo, mafh, mafl);
    hipLaunchKernelGGL(k_attn, dim3(NTR_, B_), dim3(256), 0, stream,
                       mafh, mafl, mbb_hi, mbb_lo, mbp, wcf, bc, out);
}

// Round 6
// 81.879 us; speedup vs baseline: 1.6129x; 1.1301x over previous
//
#include <hip/hip_runtime.h>

typedef float f32x4 __attribute__((ext_vector_type(4)));
typedef short s16x8 __attribute__((ext_vector_type(8)));

#define MFMA16(a, b, c) __builtin_amdgcn_mfma_f32_16x16x32_bf16((a), (b), (c), 0, 0, 0)

#define B_ 16
#define M_ 6209
#define F_ 256
#define NTR_ 389   // real 16-row tiles (389*16 = 6224 >= 6209)
#define NT_ 392    // padded tile count

static __device__ __forceinline__ unsigned short f2bf(float x) {
    unsigned u = __builtin_bit_cast(unsigned, x);
    unsigned r = u + 0x7fffu + ((u >> 16) & 1u);
    return (unsigned short)(r >> 16);
}
static __device__ __forceinline__ float bf2f(unsigned short h) {
    unsigned u = ((unsigned)h) << 16;
    return __builtin_bit_cast(float, u);
}
static __device__ __forceinline__ void split_bf(float x, unsigned short& hi, unsigned short& lo) {
    hi = f2bf(x);
    lo = f2bf(x - bf2f(hi));
}
static __device__ __forceinline__ unsigned cvtpk_bf16(float a, float b) {
    unsigned r;
    asm("v_cvt_pk_bf16_f32 %0, %1, %2" : "=v"(r) : "v"(a), "v"(b));
    return r;   // lo16 = bf(a), hi16 = bf(b)
}

// swizzled u16 index: XOR key (row&7)<<3 spreads banks, preserves 8-u16 chunks
#define SW64(row, k)  ((row) * 64 + ((k) ^ (((row) & 7) << 3)))
#define SW256(row, k) ((row) * 256 + ((k) ^ (((row) & 7) << 3)))

// ---------------- L1: mapped_b (exact fp32) + waf/wcf pack (independent of mb) ----
// blocks 0..1023: mapped_b, 4 j-rows per block (wave = one row)
// blocks 1024..1151: pack Wa (split) and Wc (single) fragment buffers
__global__ __launch_bounds__(256) void k_prep(
    const float* __restrict__ inB, const float* __restrict__ Wb, const float* __restrict__ bb,
    const float* __restrict__ Wa, const float* __restrict__ Wc,
    float* __restrict__ mb,
    unsigned short* __restrict__ waf_hi, unsigned short* __restrict__ waf_lo,
    unsigned short* __restrict__ wcf) {
    const int blk = blockIdx.x;
    if (blk < 1024) {
        const int b = blk >> 6;
        const int j = (blk & 63) * 4 + (threadIdx.x >> 6);
        const int h = threadIdx.x & 63;
        const float* src = inB + ((size_t)(b * 256 + j)) * 256;
        float s = bb[h];
        #pragma unroll 4
        for (int f4 = 0; f4 < 64; ++f4) {
            const f32x4 v = *(const f32x4*)(src + f4 * 4);
            s = fmaf(v[0], Wb[(f4 * 4 + 0) * 64 + h], s);
            s = fmaf(v[1], Wb[(f4 * 4 + 1) * 64 + h], s);
            s = fmaf(v[2], Wb[(f4 * 4 + 2) * 64 + h], s);
            s = fmaf(v[3], Wb[(f4 * 4 + 3) * 64 + h], s);
        }
        mb[((size_t)(b * 256 + j)) * 64 + h] = s;
    } else {
        const int idx = (blk - 1024) * 256 + threadIdx.x;   // 0..32767
        if (idx < 16384) {                      // WaF: K=256(f), N=64(h), split
            int i = idx;
            int jj = i & 7, lane = (i >> 3) & 63, nf = (i >> 9) & 3, ks = i >> 11;
            int g = lane >> 4, c = lane & 15;
            int f = ks * 32 + g * 8 + jj, h = nf * 16 + c;
            unsigned short hi, lo; split_bf(Wa[f * 64 + h], hi, lo);
            waf_hi[i] = hi; waf_lo[i] = lo;
        } else {                                // WcF: K=64(h), N=256(f), single
            int i = idx - 16384;
            int jj = i & 7, lane = (i >> 3) & 63, nf = (i >> 9) & 15, ks = i >> 13;
            int g = lane >> 4, c = lane & 15;
            int h = ks * 32 + g * 8 + jj, f = nf * 16 + c;
            wcf[i] = f2bf(Wc[h * 256 + f]);
        }
    }
}

// ---------------- L2: ma GEMM (2 tiles/wave, B-frag reuse) + mbb/mbp pack ----------
// blocks 0..783: ma; wave w of block (b=blk/49, bx=blk%49) handles tiles t0, t0+1
// blocks 784..2831: pack mbb (split) and mbp (single) from mb
__global__ __launch_bounds__(256, 3) void k_mapk(
    const float* __restrict__ A, const float* __restrict__ ba,
    const unsigned short* __restrict__ waf_hi, const unsigned short* __restrict__ waf_lo,
    const float* __restrict__ mb,
    unsigned short* __restrict__ mbb_hi, unsigned short* __restrict__ mbb_lo,
    unsigned short* __restrict__ mbp,
    unsigned short* __restrict__ mafh, unsigned short* __restrict__ mafl) {
    __shared__ __align__(16) unsigned short maH[4][2][1024];
    __shared__ __align__(16) unsigned short maL[4][2][1024];
    const int blk = blockIdx.x;
    if (blk < 784) {
        const int b = blk / 49, bx = blk % 49;
        const int w = threadIdx.x >> 6, lane = threadIdx.x & 63;
        const int g = lane >> 4, c = lane & 15;
        const int t0 = (bx * 4 + w) * 2;            // tiles t0, t0+1 (< 392)

        f32x4 accA[2][4];
        #pragma unroll
        for (int i = 0; i < 2; ++i)
            #pragma unroll
            for (int nf = 0; nf < 4; ++nf) { float v = ba[nf * 16 + c]; accA[i][nf] = (f32x4){v, v, v, v}; }
        const float* ab[2];
        #pragma unroll
        for (int i = 0; i < 2; ++i) {
            int arow = (t0 + i) * 16 + c; if (arow > M_ - 1) arow = M_ - 1;
            ab[i] = A + ((size_t)b * M_ + arow) * F_;
        }
        #pragma unroll
        for (int ks = 0; ks < 8; ++ks) {
            s16x8 ah[2], al[2];
            #pragma unroll
            for (int i = 0; i < 2; ++i) {
                const f32x4 a0 = *(const f32x4*)(ab[i] + ks * 32 + g * 8);
                const f32x4 a1 = *(const f32x4*)(ab[i] + ks * 32 + g * 8 + 4);
                #pragma unroll
                for (int j = 0; j < 4; ++j) {
                    unsigned short hi, lo;
                    split_bf(a0[j], hi, lo); ah[i][j] = (short)hi; al[i][j] = (short)lo;
                    split_bf(a1[j], hi, lo); ah[i][4 + j] = (short)hi; al[i][4 + j] = (short)lo;
                }
            }
            #pragma unroll
            for (int nf = 0; nf < 4; ++nf) {
                const int off = ((ks * 4 + nf) * 64 + lane) << 3;
                const s16x8 bh = *(const s16x8*)(waf_hi + off);
                const s16x8 bl = *(const s16x8*)(waf_lo + off);
                #pragma unroll
                for (int i = 0; i < 2; ++i) {
                    accA[i][nf] = MFMA16(ah[i], bh, accA[i][nf]);
                    accA[i][nf] = MFMA16(ah[i], bl, accA[i][nf]);
                    accA[i][nf] = MFMA16(al[i], bh, accA[i][nf]);
                }
            }
        }
        // split to LDS (D layout: row=g*4+r, col=nf*16+c), then emit B-fragments
        #pragma unroll
        for (int i = 0; i < 2; ++i)
            #pragma unroll
            for (int nf = 0; nf < 4; ++nf)
                #pragma unroll
                for (int r = 0; r < 4; ++r) {
                    unsigned short hi, lo; split_bf(accA[i][nf][r], hi, lo);
                    const int idx = SW64(g * 4 + r, nf * 16 + c);
                    maH[w][i][idx] = hi; maL[w][i][idx] = lo;
                }
        __syncthreads();
        #pragma unroll
        for (int i = 0; i < 2; ++i)
            #pragma unroll
            for (int ks = 0; ks < 2; ++ks) {
                const s16x8 fh = *(const s16x8*)&maH[w][i][SW64(c, ks * 32 + g * 8)];
                const s16x8 fl = *(const s16x8*)&maL[w][i][SW64(c, ks * 32 + g * 8)];
                const size_t off = (((size_t)(b * NT_ + t0 + i) * 2 + ks) * 64 + lane) << 3;
                *(s16x8*)(mafh + off) = fh;
                *(s16x8*)(mafl + off) = fl;
            }
    } else {
        const int i2 = (blk - 784) * 256 + threadIdx.x;   // 0..524287
        if (i2 < 262144) {                      // mbb: mb[j=nf*16+c][h=ks*32+g*8+jj] split
            int i = i2;
            int jj = i & 7, lane = (i >> 3) & 63, nf = (i >> 9) & 15, ks = (i >> 13) & 1, b = i >> 14;
            int g = lane >> 4, c = lane & 15;
            int h = ks * 32 + g * 8 + jj, j = nf * 16 + c;
            unsigned short hi, lo; split_bf(mb[((size_t)(b * 256 + j)) * 64 + h], hi, lo);
            mbb_hi[i] = hi; mbb_lo[i] = lo;
        } else {                                 // mbp: mb[j=ks*32+g*8+jj][h=nf*16+c] single
            int i = i2 - 262144;
            int jj = i & 7, lane = (i >> 3) & 63, nf = (i >> 9) & 3, ks = (i >> 11) & 7, b = i >> 14;
            int g = lane >> 4, c = lane & 15;
            int j = ks * 32 + g * 8 + jj, h = nf * 16 + c;
            mbp[i] = f2bf(mb[((size_t)(b * 256 + j)) * 64 + h]);
        }
    }
}

// ---------------- L3: fused attention + projection, 2 q-tiles per block ------------
// grid (195, 16), block 256 = 4 waves; per tile-pair the shared operands
// (mbb, mbp, wcf) are loaded once and used for both tiles' MFMAs.
// wave w: j-quarter (QK^T swapped + partial softmax), h-chunk w (PV), f-quarter (proj)
__global__ __launch_bounds__(256, 4) void k_attn2(
    const unsigned short* __restrict__ mafh, const unsigned short* __restrict__ mafl,
    const unsigned short* __restrict__ mbb_hi, const unsigned short* __restrict__ mbb_lo,
    const unsigned short* __restrict__ mbp, const unsigned short* __restrict__ wcf,
    const float* __restrict__ bc, float* __restrict__ out) {
    __shared__ __align__(16) unsigned short pSh[2][16 * 256];   // P^T bf16 [q][j] (16 KB)
    __shared__ __align__(16) unsigned short o1S[2][16 * 64];    // out1 bf16 [q][h] (4 KB)
    __shared__ float pmaxS[2][4][16];
    __shared__ float psumS[2][4][16];

    const int t0 = blockIdx.x * 2, b = blockIdx.y;
    const int w = threadIdx.x >> 6, lane = threadIdx.x & 63;
    const int g = lane >> 4, c = lane & 15;
    const float SC = 11.541560327f;   // 8 * log2(e)

    // ma fragments for both tiles (pre-packed by k_mapk)
    s16x8 bh[2][2], bl[2][2];
    #pragma unroll
    for (int i = 0; i < 2; ++i)
        #pragma unroll
        for (int ks = 0; ks < 2; ++ks) {
            const size_t off = (((size_t)(b * NT_ + t0 + i) * 2 + ks) * 64 + lane) << 3;
            bh[i][ks] = *(const s16x8*)(mafh + off);
            bl[i][ks] = *(const s16x8*)(mafl + off);
        }

    // ---- QK^T (swapped): S^T[j = (w*4+jtl)*16 + g*4 + r][q = c], j-quarter w ----
    f32x4 accST[2][4];
    #pragma unroll
    for (int i = 0; i < 2; ++i)
        #pragma unroll
        for (int jtl = 0; jtl < 4; ++jtl) accST[i][jtl] = (f32x4){0.f, 0.f, 0.f, 0.f};
    #pragma unroll
    for (int jtl = 0; jtl < 4; ++jtl) {
        const int jt = w * 4 + jtl;
        const size_t off0 = ((((size_t)b * 2 + 0) * 16 + jt) * 64 + lane) << 3;
        const size_t off1 = ((((size_t)b * 2 + 1) * 16 + jt) * 64 + lane) << 3;
        const s16x8 ah0 = *(const s16x8*)(mbb_hi + off0);
        const s16x8 al0 = *(const s16x8*)(mbb_lo + off0);
        const s16x8 ah1 = *(const s16x8*)(mbb_hi + off1);
        const s16x8 al1 = *(const s16x8*)(mbb_lo + off1);
        #pragma unroll
        for (int i = 0; i < 2; ++i) {
            f32x4 acc = accST[i][jtl];
            acc = MFMA16(ah0, bh[i][0], acc);
            acc = MFMA16(ah1, bh[i][1], acc);
            acc = MFMA16(ah0, bl[i][0], acc);
            acc = MFMA16(ah1, bl[i][1], acc);
            acc = MFMA16(al0, bh[i][0], acc);
            acc = MFMA16(al1, bh[i][1], acc);
            accST[i][jtl] = acc;
        }
    }

    // ---- partial softmax: wave-local max over 64 j for q=c (per tile) ----
    #pragma unroll
    for (int i = 0; i < 2; ++i) {
        float m = accST[i][0][0];
        #pragma unroll
        for (int jtl = 0; jtl < 4; ++jtl) {
            m = fmaxf(m, accST[i][jtl][0]); m = fmaxf(m, accST[i][jtl][1]);
            m = fmaxf(m, accST[i][jtl][2]); m = fmaxf(m, accST[i][jtl][3]);
        }
        m = fmaxf(m, __shfl_xor(m, 16));
        m = fmaxf(m, __shfl_xor(m, 32));
        if (lane < 16) pmaxS[i][w][lane] = m;
    }
    __syncthreads();   // B1: pmaxS ready

    #pragma unroll
    for (int i = 0; i < 2; ++i) {
        const float mg = fmaxf(fmaxf(pmaxS[i][0][c], pmaxS[i][1][c]),
                               fmaxf(pmaxS[i][2][c], pmaxS[i][3][c]));
        float s = 0.f;
        #pragma unroll
        for (int jtl = 0; jtl < 4; ++jtl) {
            f32x4 p;
            #pragma unroll
            for (int r = 0; r < 4; ++r) {
                p[r] = __builtin_amdgcn_exp2f((accST[i][jtl][r] - mg) * SC);
                s += p[r];
            }
            const unsigned w0 = cvtpk_bf16(p[0], p[1]);
            const unsigned w1 = cvtpk_bf16(p[2], p[3]);
            const unsigned long long wv = (unsigned long long)w0 | ((unsigned long long)w1 << 32);
            *(unsigned long long*)&pSh[i][SW256(c, (w * 4 + jtl) * 16 + g * 4)] = wv;
        }
        s += __shfl_xor(s, 16);
        s += __shfl_xor(s, 32);
        if (lane < 16) psumS[i][w][lane] = s;
    }
    __syncthreads();   // B2: pSh + psumS ready

    // ---- PV: out1^T[h = w*16+g*4+r][q = c], K=256; mbp frag shared by both tiles ----
    f32x4 acc1[2] = {(f32x4){0.f, 0.f, 0.f, 0.f}, (f32x4){0.f, 0.f, 0.f, 0.f}};
    #pragma unroll
    for (int ks = 0; ks < 8; ++ks) {
        const size_t off = ((((size_t)b * 8 + ks) * 4 + w) * 64 + lane) << 3;
        const s16x8 av = *(const s16x8*)(mbp + off);
        #pragma unroll
        for (int i = 0; i < 2; ++i) {
            const s16x8 pf = *(const s16x8*)&pSh[i][SW256(c, ks * 32 + g * 8)];
            acc1[i] = MFMA16(av, pf, acc1[i]);
        }
    }
    #pragma unroll
    for (int i = 0; i < 2; ++i) {
        const float rinv = 1.f / (psumS[i][0][c] + psumS[i][1][c] + psumS[i][2][c] + psumS[i][3][c]);
        const unsigned w0 = cvtpk_bf16(acc1[i][0] * rinv, acc1[i][1] * rinv);
        const unsigned w1 = cvtpk_bf16(acc1[i][2] * rinv, acc1[i][3] * rinv);
        const unsigned long long wv = (unsigned long long)w0 | ((unsigned long long)w1 << 32);
        *(unsigned long long*)&o1S[i][SW64(c, w * 16 + g * 4)] = wv;
    }
    __syncthreads();   // B3: o1S ready

    // ---- projection f-quarter w: out = out1 @ Wc + bc; wcf frags shared ----
    s16x8 af[2][2];
    #pragma unroll
    for (int i = 0; i < 2; ++i)
        #pragma unroll
        for (int ks = 0; ks < 2; ++ks)
            af[i][ks] = *(const s16x8*)&o1S[i][SW64(c, ks * 32 + g * 8)];
    #pragma unroll
    for (int ftl = 0; ftl < 4; ++ftl) {
        const int ft = w * 4 + ftl;
        const float bv = bc[ft * 16 + c];
        const s16x8 wb0 = *(const s16x8*)(wcf + (((0 * 16 + ft) * 64 + lane) << 3));
        const s16x8 wb1 = *(const s16x8*)(wcf + (((1 * 16 + ft) * 64 + lane) << 3));
        #pragma unroll
        for (int i = 0; i < 2; ++i) {
            f32x4 acc = (f32x4){bv, bv, bv, bv};
            acc = MFMA16(af[i][0], wb0, acc);
            acc = MFMA16(af[i][1], wb1, acc);
            #pragma unroll
            for (int r = 0; r < 4; ++r) {
                const int q = (t0 + i) * 16 + g * 4 + r;
                if (q < M_) out[((size_t)b * M_ + q) * F_ + ft * 16 + c] = acc[r];
            }
        }
    }
}

extern "C" void kernel_launch(void* const* d_in, const int* in_sizes, int n_in,
                              void* d_out, int out_size, void* d_ws, size_t ws_size,
                              hipStream_t stream) {
    (void)in_sizes; (void)n_in; (void)out_size; (void)ws_size;
    const float* inA = (const float*)d_in[0];
    const float* inB = (const float*)d_in[1];
    const float* Wa  = (const float*)d_in[2];
    const float* ba  = (const float*)d_in[3];
    const float* Wb  = (const float*)d_in[4];
    const float* bb  = (const float*)d_in[5];
    const float* Wc  = (const float*)d_in[6];
    const float* bc  = (const float*)d_in[7];
    float* out = (float*)d_out;

    char* ws = (char*)d_ws;
    float* mb              = (float*)ws;                          // @0        1,048,576 B
    unsigned short* waf_hi = (unsigned short*)(ws + 1048576);     //    32,768 B
    unsigned short* waf_lo = (unsigned short*)(ws + 1081344);     //    32,768 B
    unsigned short* wcf    = (unsigned short*)(ws + 1114112);     //    32,768 B
    unsigned short* mbb_hi = (unsigned short*)(ws + 1146880);     //   524,288 B
    unsigned short* mbb_lo = (unsigned short*)(ws + 1671168);     //   524,288 B
    unsigned short* mbp    = (unsigned short*)(ws + 2195456);     //   524,288 B (ends 2,719,744)
    unsigned short* mafh   = (unsigned short*)(ws + 2719744);     // 12,845,056 B (16*392*2*64*8 u16)
    unsigned short* mafl   = (unsigned short*)(ws + 15564800);    // 12,845,056 B (ends 28,409,856)

    hipLaunchKernelGGL(k_prep, dim3(1024 + 128), dim3(256), 0, stream,
                       inB, Wb, bb, Wa, Wc, mb, waf_hi, waf_lo, wcf);
    hipLaunchKernelGGL(k_mapk, dim3(784 + 2048), dim3(256), 0, stream,
                       inA, ba, waf_hi, waf_lo, mb, mbb_hi, mbb_lo, mbp, mafh, mafl);
    hipLaunchKernelGGL(k_attn2, dim3(195, B_), dim3(256), 0, stream,
                       mafh, mafl, mbb_hi, mbb_lo, mbp, wcf, bc, out);
}